// Round 16
// baseline (312.433 us; speedup 1.0000x reference)
//
#include <hip/hip_runtime.h>
#include <hip/hip_bf16.h>

typedef unsigned int u32;
typedef unsigned short u16;
typedef __attribute__((ext_vector_type(8))) short short8;
typedef __attribute__((ext_vector_type(4))) float f32x4;
typedef __attribute__((ext_vector_type(2))) u32 u32x2;

#define B_      128
#define N_      4096
#define K_      8
#define SCALE_  0.125f
#define EPS_A   1e-8f
#define EPS_LN  1e-5f

__device__ __forceinline__ float bf_lo(u32 u){ union{u32 v; float f;} x; x.v = u<<16; return x.f; }
__device__ __forceinline__ u16 f2bf(float f){
  union{float f; u32 v;} x; x.f = f;
  u32 v = x.v;
  return (u16)((v + 0x7fffu + ((v>>16)&1u))>>16);   // RNE
}
__device__ __forceinline__ float wsum64(float v){
  #pragma unroll
  for (int off=32; off; off>>=1) v += __shfl_xor(v, off, 64);
  return v;
}
__device__ __forceinline__ void gll16(const void* g, void* l){
  __builtin_amdgcn_global_load_lds(
      (const __attribute__((address_space(1))) void*)g,
      (__attribute__((address_space(3))) void*)l, 16, 0, 0);
}

// ---- one-time prep: transpose GRU weights; Wqk = Wq @ Wk^T ----
__global__ void prep_t(const float* __restrict__ Wih, const float* __restrict__ Whh,
                       const float* __restrict__ Wq,  const float* __restrict__ Wk,
                       float* __restrict__ WihT, float* __restrict__ WhhT,
                       float* __restrict__ Wqk){
  int t = threadIdx.x;
  if (blockIdx.x < 48){
    int idx = blockIdx.x*256 + t;            // 12288 = 192*64
    int g = idx>>6, d = idx&63;
    WihT[d*192+g] = Wih[idx];
    WhhT[d*192+g] = Whh[idx];
  } else {
    __shared__ float WkL[64*65];
    int bi = blockIdx.x - 48;                // 0..15
    #pragma unroll
    for (int k=0;k<16;++k){
      int idx = t + k*256;
      int d = idx>>6, m = idx&63;
      WkL[m*65+d] = Wk[idx];
    }
    __syncthreads();
    int a = bi*4 + (t>>6), d = t&63;
    float acc = 0.f;
    #pragma unroll 8
    for (int m=0;m<64;++m) acc += Wq[a*64+m]*WkL[m*65+d];
    Wqk[a*64+d] = acc;
  }
}

// per-tile attention phases (R11-verified byte math; 32-pos x 64-d image in ibuf)
__device__ __forceinline__ void tile_attn(
    char* ibuf, char* abuf, short8 qf0, short8 qf1,
    int fr, int fq, f32x4* c2, float* tsl)
{
  // ph1: dots[16 slots][32 pos]
  f32x4 c1[2];
  #pragma unroll
  for (int nt=0;nt<2;++nt){
    c1[nt] = (f32x4){0.f,0.f,0.f,0.f};
    #pragma unroll
    for (int kk=0;kk<2;++kk){
      int byte = ((kk*2+(fq>>1))<<10) | (((fr>>2)&1)<<9)
               | ((nt*2+(fr>>3))<<7) | ((fr&3)<<5) | ((fq&1)<<4);
      short8 xf = *(const short8*)(ibuf + byte);
      c1[nt] = __builtin_amdgcn_mfma_f32_16x16x32_bf16(kk?qf1:qf0, xf, c1[nt], 0,0,0);
    }
  }
  // softmax over slots; attn -> abuf [16 slots][32 pos] bf16
  #pragma unroll
  for (int nt=0;nt<2;++nt){
    float d0 = c1[nt][0]*SCALE_, d1 = c1[nt][1]*SCALE_;
    float d2 = c1[nt][2]*SCALE_, d3 = c1[nt][3]*SCALE_;
    float m = fmaxf(fmaxf(d0,d1), fmaxf(d2,d3));
    m = fmaxf(m, __shfl_xor(m, 16, 64));
    float e0 = __expf(d0-m), e1 = __expf(d1-m), e2 = __expf(d2-m), e3 = __expf(d3-m);
    float sl = e0+e1+e2+e3;
    float inv = 1.f/(sl + __shfl_xor(sl, 16, 64));
    float a0 = e0*inv + EPS_A, a1 = e1*inv + EPS_A;
    float a2 = e2*inv + EPS_A, a3 = e3*inv + EPS_A;
    tsl[0]+=a0; tsl[1]+=a1; tsl[2]+=a2; tsl[3]+=a3;
    int pos2 = (nt*16 + fr)*2;
    *(u16*)(abuf + (((fq*4+0)*64 + pos2) ^ (0<<4))) = f2bf(a0);
    *(u16*)(abuf + (((fq*4+1)*64 + pos2) ^ (1<<4))) = f2bf(a1);
    *(u16*)(abuf + (((fq*4+2)*64 + pos2) ^ (2<<4))) = f2bf(a2);
    *(u16*)(abuf + (((fq*4+3)*64 + pos2) ^ (3<<4))) = f2bf(a3);
  }
  asm volatile("s_waitcnt lgkmcnt(0)" ::: "memory");
  __builtin_amdgcn_sched_barrier(0);
  // ph2: U[slot][d] += attn @ x^T  (all 64 d, K=32 pos)
  {
    short8 pa = *(const short8*)(abuf + ((fr*64 + fq*16) ^ ((fr&3)<<4)));
    u32 va = (u32)(size_t)ibuf + (fq<<7) + (fr<<1);
    u32x2 tv0,tv1,tv2,tv3,tv4,tv5,tv6,tv7;
    asm volatile("ds_read_b64_tr_b16 %0, %1 offset:0"    : "=v"(tv0) : "v"(va));
    asm volatile("ds_read_b64_tr_b16 %0, %1 offset:512"  : "=v"(tv1) : "v"(va));
    asm volatile("ds_read_b64_tr_b16 %0, %1 offset:1024" : "=v"(tv2) : "v"(va));
    asm volatile("ds_read_b64_tr_b16 %0, %1 offset:1536" : "=v"(tv3) : "v"(va));
    asm volatile("ds_read_b64_tr_b16 %0, %1 offset:2048" : "=v"(tv4) : "v"(va));
    asm volatile("ds_read_b64_tr_b16 %0, %1 offset:2560" : "=v"(tv5) : "v"(va));
    asm volatile("ds_read_b64_tr_b16 %0, %1 offset:3072" : "=v"(tv6) : "v"(va));
    asm volatile("ds_read_b64_tr_b16 %0, %1 offset:3584" : "=v"(tv7) : "v"(va));
    asm volatile("s_waitcnt lgkmcnt(0)" ::: "memory");
    __builtin_amdgcn_sched_barrier(0);
    union { short8 s8; u32 u4[4]; } xb;
    xb.u4[0]=tv0.x; xb.u4[1]=tv0.y; xb.u4[2]=tv1.x; xb.u4[3]=tv1.y;
    c2[0] = __builtin_amdgcn_mfma_f32_16x16x32_bf16(pa, xb.s8, c2[0], 0,0,0);
    xb.u4[0]=tv2.x; xb.u4[1]=tv2.y; xb.u4[2]=tv3.x; xb.u4[3]=tv3.y;
    c2[1] = __builtin_amdgcn_mfma_f32_16x16x32_bf16(pa, xb.s8, c2[1], 0,0,0);
    xb.u4[0]=tv4.x; xb.u4[1]=tv4.y; xb.u4[2]=tv5.x; xb.u4[3]=tv5.y;
    c2[2] = __builtin_amdgcn_mfma_f32_16x16x32_bf16(pa, xb.s8, c2[2], 0,0,0);
    xb.u4[0]=tv6.x; xb.u4[1]=tv6.y; xb.u4[2]=tv7.x; xb.u4[3]=tv7.y;
    c2[3] = __builtin_amdgcn_mfma_f32_16x16x32_bf16(pa, xb.s8, c2[3], 0,0,0);
  }
}

// ---- whole slot-attention loop: 1 block/batch, 16 waves, 3 iters ----
__global__ __launch_bounds__(1024,1) void fused_sa(
    const float* __restrict__ inp, u16* __restrict__ xhat,
    const float* __restrict__ noise, const float* __restrict__ mu, const float* __restrict__ sigma,
    const float* __restrict__ Wqk,
    const float* __restrict__ lng, const float* __restrict__ lnb,
    const float* __restrict__ lnsg, const float* __restrict__ lnsb,
    const float* __restrict__ WihT, const float* __restrict__ WhhT,
    const float* __restrict__ bih, const float* __restrict__ bhh,
    const float* __restrict__ W1, const float* __restrict__ b1,
    const float* __restrict__ W2, const float* __restrict__ b2,
    const float* __restrict__ lnffg, const float* __restrict__ lnffb,
    const float* __restrict__ Wv,
    float* __restrict__ dout)
{
  // LDS map (149504 B):
  //  [0,147456)      16 per-wave stream areas, w*9216: image dbuf 2x4KB + abuf 1KB
  //     alias after streaming: UL_w = area+0 (2KB), SL_w = area+2048 (32B)
  //     alias in update: updL=area8+4096, spL=area9+4096, sfL=area10+4096, hL=area11+4096
  //  [147456,149504) qA [16][64] bf16, elem (i,d) at (i*128+d*2)^((i&7)<<4)
  __shared__ __align__(16) char smem[149504];
  int b = blockIdx.x, t = threadIdx.x;
  int w = t>>6, lane = t&63;
  int fr = lane&15, fq = lane>>4;
  int i = (t>>6)&7, d = lane;                // update coords (slot, dim), t<512

  char*  wbase = smem + w*9216;
  char*  abuf  = wbase + 8192;
  char*  qA    = smem + 147456;
  float* updL  = (float*)(smem +  8*9216 + 4096);
  float* spL   = (float*)(smem +  9*9216 + 4096);
  float* sfL   = (float*)(smem + 10*9216 + 4096);
  float* hL    = (float*)(smem + 11*9216 + 4096);

  // ---- init: zero qA pad; slots0 + q-tilde0 (threads t<512) ----
  if (t < 256) ((u32*)(qA + 1024))[t] = 0;   // zero pad rows 8..15
  float sp = 0.f;
  if (t < 512){
    sp = mu[d] + sigma[d]*noise[b*512 + t];
    float m  = wsum64(sp)*(1.f/64.f);
    float df = sp - m;
    float vv = wsum64(df*df)*(1.f/64.f);
    float sv = df*rsqrtf(vv+EPS_LN)*lnsg[d] + lnsb[d];
    updL[i*68+d] = sv;
  }
  __syncthreads();
  if (t < 512){
    float qt = 0.f;
    #pragma unroll 8
    for (int dd=0; dd<64; ++dd) qt += updL[i*68+dd]*Wqk[dd*64 + d];
    *(u16*)(qA + ((i*128 + d*2) ^ ((i&7)<<4))) = f2bf(qt);
  }
  __syncthreads();

  long tbase = (long)b*128 + w*8;            // this wave's global 4KB-tile base

  for (int it=0; it<3; ++it){
    // ================= streaming phase (16 waves, no block barriers) =========
    f32x4 c2[4];
    #pragma unroll
    for (int k2=0;k2<4;++k2) c2[k2] = (f32x4){0.f,0.f,0.f,0.f};
    float tsl[4] = {0.f,0.f,0.f,0.f};
    short8 qf0 = *(const short8*)(qA + ((fr*128 +  0 + fq*16) ^ ((fr&7)<<4)));
    short8 qf1 = *(const short8*)(qA + ((fr*128 + 64 + fq*16) ^ ((fr&7)<<4)));

    if (it == 0){
      // LN from f32 inputs, build image, store image to global, attend
      for (int tile=0; tile<8; ++tile){
        char* ibuf = wbase;
        {
          int r = lane>>1, hx = lane&1;
          const float4* xr = (const float4*)(inp +
              ((long)b*N_ + w*256 + tile*32 + r)*64 + hx*32);
          float xv[32]; float s=0.f, sq=0.f;
          #pragma unroll
          for (int c=0;c<8;++c){
            float4 f = xr[c];
            xv[c*4+0]=f.x; xv[c*4+1]=f.y; xv[c*4+2]=f.z; xv[c*4+3]=f.w;
            s  += f.x+f.y+f.z+f.w;
            sq += f.x*f.x+f.y*f.y+f.z*f.z+f.w*f.w;
          }
          s  += __shfl_xor(s,1,64);
          sq += __shfl_xor(sq,1,64);
          float mean = s*(1.f/64.f);
          float inv  = rsqrtf(sq*(1.f/64.f) - mean*mean + EPS_LN);
          float lgv[32], lbv[32];
          {
            const float4* g4 = (const float4*)(lng + hx*32);
            const float4* b4 = (const float4*)(lnb + hx*32);
            #pragma unroll
            for (int e=0;e<8;++e){
              float4 gv = g4[e], bv = b4[e];
              lgv[e*4+0]=gv.x; lgv[e*4+1]=gv.y; lgv[e*4+2]=gv.z; lgv[e*4+3]=gv.w;
              lbv[e*4+0]=bv.x; lbv[e*4+1]=bv.y; lbv[e*4+2]=bv.z; lbv[e*4+3]=bv.w;
            }
          }
          u32 pk[16];
          #pragma unroll
          for (int e=0;e<16;++e){
            float a0 = (xv[e*2]  -mean)*inv*lgv[e*2]   + lbv[e*2];
            float a1 = (xv[e*2+1]-mean)*inv*lgv[e*2+1] + lbv[e*2+1];
            pk[e] = (u32)f2bf(a0) | ((u32)f2bf(a1)<<16);
          }
          int pbits = (((r>>2)&1)<<9) | (((r>>3)&3)<<7) | ((r&3)<<5);
          #pragma unroll
          for (int hf=0; hf<2; ++hf){
            int dt = hx*2 + hf;
            uint4 v0; v0.x=pk[hf*8+0]; v0.y=pk[hf*8+1]; v0.z=pk[hf*8+2]; v0.w=pk[hf*8+3];
            uint4 v1; v1.x=pk[hf*8+4]; v1.y=pk[hf*8+5]; v1.z=pk[hf*8+6]; v1.w=pk[hf*8+7];
            *(uint4*)(ibuf + ((dt<<10) | pbits))      = v0;
            *(uint4*)(ibuf + ((dt<<10) | pbits) + 16) = v1;
          }
          asm volatile("s_waitcnt lgkmcnt(0)" ::: "memory");
          __builtin_amdgcn_sched_barrier(0);
          char* gim = (char*)xhat + ((tbase+tile)<<12) + lane*16;
          #pragma unroll
          for (int j=0;j<4;++j)
            *(uint4*)(gim + j*1024) = *(const uint4*)(ibuf + lane*16 + j*1024);
        }
        tile_attn(ibuf, abuf, qf0, qf1, fr, fq, c2, tsl);
      }
      asm volatile("s_waitcnt vmcnt(0)" ::: "memory");  // image stores done
      __builtin_amdgcn_sched_barrier(0);
    } else {
      // gll16-streamed, per-wave double-buffered
      {
        const char* g0 = (const char*)xhat + (tbase<<12) + lane*16;
        #pragma unroll
        for (int j=0;j<4;++j) gll16(g0 + j*1024, wbase + j*1024);
      }
      #pragma unroll 2
      for (int tile=0; tile<8; ++tile){
        char* ibuf = wbase + (tile&1)*4096;
        if (tile < 7){
          const char* gn = (const char*)xhat + ((tbase+tile+1)<<12) + lane*16;
          char* ln = wbase + ((tile+1)&1)*4096;
          #pragma unroll
          for (int j=0;j<4;++j) gll16(gn + j*1024, ln + j*1024);
          asm volatile("s_waitcnt vmcnt(4)" ::: "memory");
        } else {
          asm volatile("s_waitcnt vmcnt(0)" ::: "memory");
        }
        __builtin_amdgcn_sched_barrier(0);
        tile_attn(ibuf, abuf, qf0, qf1, fr, fq, c2, tsl);
      }
    }
    // ---- per-wave partials into own (now-dead) stream area ----
    {
      float* ULw = (float*)wbase;              // 512 floats
      float* SLw = (float*)(wbase + 2048);     // 8 floats
      if (fq < 2){
        #pragma unroll
        for (int dblk=0;dblk<4;++dblk){
          #pragma unroll
          for (int r=0;r<4;++r)
            ULw[(fq*4+r)*64 + dblk*16 + fr] = c2[dblk][r];
        }
      }
      #pragma unroll
      for (int mk=1; mk<16; mk<<=1){
        tsl[0] += __shfl_xor(tsl[0], mk, 64);
        tsl[1] += __shfl_xor(tsl[1], mk, 64);
        tsl[2] += __shfl_xor(tsl[2], mk, 64);
        tsl[3] += __shfl_xor(tsl[3], mk, 64);
      }
      if (fr==0 && fq<2){
        SLw[fq*4+0] = tsl[0]; SLw[fq*4+1] = tsl[1];
        SLw[fq*4+2] = tsl[2]; SLw[fq*4+3] = tsl[3];
      }
    }
    __syncthreads();

    // ================= update phase (threads t<512) =================
    if (t < 512){
      float u = 0.f, S = 0.f;
      #pragma unroll
      for (int cw=0; cw<16; ++cw){
        u += ((const float*)(smem + cw*9216))[i*64 + d];
        S += ((const float*)(smem + cw*9216 + 2048))[i];
      }
      float ut = u / S;
      sfL[i*68+d] = ut;
      spL[i*68+d] = sp;
    }
    __syncthreads();
    if (t < 512){
      float upd = 0.f;
      #pragma unroll 8
      for (int dd=0; dd<64; ++dd) upd += sfL[i*68+dd]*Wv[dd*64 + d];
      updL[i*68+d] = upd;
    }
    __syncthreads();
    float out = 0.f;
    if (t < 512){
      float gx0 = bih[d], gx1 = bih[64+d], gx2 = bih[128+d];
      float gh0 = bhh[d], gh1 = bhh[64+d], gh2 = bhh[128+d];
      #pragma unroll 8
      for (int dd=0; dd<64; ++dd){
        float uv = updL[i*68+dd];
        float sv = spL[i*68+dd];
        gx0 += uv*WihT[dd*192 + d];
        gx1 += uv*WihT[dd*192 + 64 + d];
        gx2 += uv*WihT[dd*192 + 128 + d];
        gh0 += sv*WhhT[dd*192 + d];
        gh1 += sv*WhhT[dd*192 + 64 + d];
        gh2 += sv*WhhT[dd*192 + 128 + d];
      }
      float rg = 1.f/(1.f+__expf(-(gx0+gh0)));
      float zg = 1.f/(1.f+__expf(-(gx1+gh1)));
      float ng = tanhf(gx2 + rg*gh2);
      float sn = (1.f-zg)*ng + zg*sp;
      float m1 = wsum64(sn)*(1.f/64.f);
      float df = sn-m1;
      float vv = wsum64(df*df)*(1.f/64.f);
      float sf = df*rsqrtf(vv+EPS_LN)*lnffg[d] + lnffb[d];
      sfL[i*68+d] = sf;
      out = sf;   // carry sf through
    }
    __syncthreads();
    if (t < 512){
      float h0 = b1[d], h1 = b1[64+d];
      #pragma unroll 8
      for (int dd=0;dd<64;++dd){
        float sv = sfL[i*68+dd];
        h0 += sv*W1[dd*128 + d];
        h1 += sv*W1[dd*128 + 64 + d];
      }
      h0 = fmaxf(h0, 0.f); h1 = fmaxf(h1, 0.f);
      hL[i*132+d] = h0; hL[i*132+64+d] = h1;
    }
    __syncthreads();
    if (t < 512){
      float o = b2[d];
      #pragma unroll 8
      for (int hh=0; hh<128; ++hh) o += hL[i*132+hh]*W2[hh*64 + d];
      out = out + o;            // sf + mlp
      sp = out;
      if (it == 2){
        dout[b*512 + t] = out;
      } else {
        float m2 = wsum64(out)*(1.f/64.f);
        float d2 = out-m2;
        float v2 = wsum64(d2*d2)*(1.f/64.f);
        float sq = d2*rsqrtf(v2+EPS_LN)*lnsg[d] + lnsb[d];
        updL[i*68+d] = sq;
      }
    }
    __syncthreads();
    if (it < 2){
      if (t < 512){
        float qt = 0.f;
        #pragma unroll 8
        for (int dd=0;dd<64;++dd) qt += updL[i*68+dd]*Wqk[dd*64 + d];
        *(u16*)(qA + ((i*128 + d*2) ^ ((i&7)<<4))) = f2bf(qt);
      }
      __syncthreads();
    }
  }
}

extern "C" void kernel_launch(void* const* d_in, const int* in_sizes, int n_in,
                              void* d_out, int out_size, void* d_ws, size_t ws_size,
                              hipStream_t stream){
  const float* inp   = (const float*)d_in[0];
  const float* noise = (const float*)d_in[1];
  const float* mu    = (const float*)d_in[2];
  const float* sigma = (const float*)d_in[3];
  const float* Wq    = (const float*)d_in[4];
  const float* Wk    = (const float*)d_in[5];
  const float* Wv    = (const float*)d_in[6];
  const float* Wih   = (const float*)d_in[7];
  const float* Whh   = (const float*)d_in[8];
  const float* bih   = (const float*)d_in[9];
  const float* bhh   = (const float*)d_in[10];
  const float* W1    = (const float*)d_in[11];
  const float* b1    = (const float*)d_in[12];
  const float* W2    = (const float*)d_in[13];
  const float* b2    = (const float*)d_in[14];
  const float* lnig  = (const float*)d_in[15];
  const float* lnib  = (const float*)d_in[16];
  const float* lnsg  = (const float*)d_in[17];
  const float* lnsb  = (const float*)d_in[18];
  const float* lnffg = (const float*)d_in[19];
  const float* lnffb = (const float*)d_in[20];
  float* out = (float*)d_out;

  char* ws = (char*)d_ws;
  u16*   xhat = (u16*)(ws);                        // 67108864 B (4KB tile images)
  float* WihT = (float*)(ws + 67108864);           // 49152 B
  float* WhhT = (float*)(ws + 67158016);           // 49152 B
  float* Wqk  = (float*)(ws + 67207168);           // 16384 B -> ~67.2 MB total

  prep_t<<<64,256,0,stream>>>(Wih, Whh, Wq, Wk, WihT, WhhT, Wqk);
  fused_sa<<<B_,1024,0,stream>>>(inp, xhat, noise, mu, sigma, Wqk,
                                 lnig, lnib, lnsg, lnsb,
                                 WihT, WhhT, bih, bhh,
                                 W1, b1, W2, b2, lnffg, lnffb, Wv, out);
}

// Round 17
// 147.921 us; speedup vs baseline: 2.1122x; 2.1122x over previous
//
#include <hip/hip_runtime.h>
#include <hip/hip_bf16.h>

typedef unsigned int u32;
typedef unsigned short u16;
typedef __attribute__((ext_vector_type(8))) short short8;
typedef __attribute__((ext_vector_type(4))) float f32x4;
typedef __attribute__((ext_vector_type(2))) u32 u32x2;

#define B_      128
#define N_      4096
#define K_      8
#define SCALE_  0.125f
#define EPS_A   1e-8f
#define EPS_LN  1e-5f

__device__ __forceinline__ float bf_lo(u32 u){ union{u32 v; float f;} x; x.v = u<<16; return x.f; }
__device__ __forceinline__ u16 f2bf(float f){
  union{float f; u32 v;} x; x.f = f;
  u32 v = x.v;
  return (u16)((v + 0x7fffu + ((v>>16)&1u))>>16);   // RNE
}
__device__ __forceinline__ float wsum64(float v){
  #pragma unroll
  for (int off=32; off; off>>=1) v += __shfl_xor(v, off, 64);
  return v;
}
__device__ __forceinline__ void gll16(const void* g, void* l){
  __builtin_amdgcn_global_load_lds(
      (const __attribute__((address_space(1))) void*)g,
      (__attribute__((address_space(3))) void*)l, 16, 0, 0);
}

// ---- one-time prep: transpose GRU weights; Wqk = Wq @ Wk^T ----
__global__ void prep_t(const float* __restrict__ Wih, const float* __restrict__ Whh,
                       const float* __restrict__ Wq,  const float* __restrict__ Wk,
                       float* __restrict__ WihT, float* __restrict__ WhhT,
                       float* __restrict__ Wqk){
  int t = threadIdx.x;
  if (blockIdx.x < 48){
    int idx = blockIdx.x*256 + t;            // 12288 = 192*64
    int g = idx>>6, d = idx&63;
    WihT[d*192+g] = Wih[idx];
    WhhT[d*192+g] = Whh[idx];
  } else {
    __shared__ float WkL[64*65];
    int bi = blockIdx.x - 48;                // 0..15
    #pragma unroll
    for (int k=0;k<16;++k){
      int idx = t + k*256;
      int d = idx>>6, m = idx&63;
      WkL[m*65+d] = Wk[idx];
    }
    __syncthreads();
    int a = bi*4 + (t>>6), d = t&63;
    float acc = 0.f;
    #pragma unroll 8
    for (int m=0;m<64;++m) acc += Wq[a*64+m]*WkL[m*65+d];
    Wqk[a*64+d] = acc;
  }
}

// per-tile attention phases (R11-verified byte math; 32-pos x 64-d image in ibuf)
__device__ __forceinline__ void tile_attn(
    char* ibuf, char* abuf, short8 qf0, short8 qf1,
    int fr, int fq, f32x4* c2, float* tsl)
{
  // ph1: dots[16 slots][32 pos]
  f32x4 c1[2];
  #pragma unroll
  for (int nt=0;nt<2;++nt){
    c1[nt] = (f32x4){0.f,0.f,0.f,0.f};
    #pragma unroll
    for (int kk=0;kk<2;++kk){
      int byte = ((kk*2+(fq>>1))<<10) | (((fr>>2)&1)<<9)
               | ((nt*2+(fr>>3))<<7) | ((fr&3)<<5) | ((fq&1)<<4);
      short8 xf = *(const short8*)(ibuf + byte);
      c1[nt] = __builtin_amdgcn_mfma_f32_16x16x32_bf16(kk?qf1:qf0, xf, c1[nt], 0,0,0);
    }
  }
  // softmax over slots; attn -> abuf [16 slots][32 pos] bf16
  #pragma unroll
  for (int nt=0;nt<2;++nt){
    float d0 = c1[nt][0]*SCALE_, d1 = c1[nt][1]*SCALE_;
    float d2 = c1[nt][2]*SCALE_, d3 = c1[nt][3]*SCALE_;
    float m = fmaxf(fmaxf(d0,d1), fmaxf(d2,d3));
    m = fmaxf(m, __shfl_xor(m, 16, 64));
    float e0 = __expf(d0-m), e1 = __expf(d1-m), e2 = __expf(d2-m), e3 = __expf(d3-m);
    float sl = e0+e1+e2+e3;
    float inv = 1.f/(sl + __shfl_xor(sl, 16, 64));
    float a0 = e0*inv + EPS_A, a1 = e1*inv + EPS_A;
    float a2 = e2*inv + EPS_A, a3 = e3*inv + EPS_A;
    tsl[0]+=a0; tsl[1]+=a1; tsl[2]+=a2; tsl[3]+=a3;
    int pos2 = (nt*16 + fr)*2;
    *(u16*)(abuf + (((fq*4+0)*64 + pos2) ^ (0<<4))) = f2bf(a0);
    *(u16*)(abuf + (((fq*4+1)*64 + pos2) ^ (1<<4))) = f2bf(a1);
    *(u16*)(abuf + (((fq*4+2)*64 + pos2) ^ (2<<4))) = f2bf(a2);
    *(u16*)(abuf + (((fq*4+3)*64 + pos2) ^ (3<<4))) = f2bf(a3);
  }
  asm volatile("s_waitcnt lgkmcnt(0)" ::: "memory");
  __builtin_amdgcn_sched_barrier(0);
  // ph2: U[slot][d] += attn @ x^T  (all 64 d, K=32 pos)
  {
    short8 pa = *(const short8*)(abuf + ((fr*64 + fq*16) ^ ((fr&3)<<4)));
    u32 va = (u32)(size_t)ibuf + (fq<<7) + (fr<<1);
    u32x2 tv0,tv1,tv2,tv3,tv4,tv5,tv6,tv7;
    asm volatile("ds_read_b64_tr_b16 %0, %1 offset:0"    : "=v"(tv0) : "v"(va));
    asm volatile("ds_read_b64_tr_b16 %0, %1 offset:512"  : "=v"(tv1) : "v"(va));
    asm volatile("ds_read_b64_tr_b16 %0, %1 offset:1024" : "=v"(tv2) : "v"(va));
    asm volatile("ds_read_b64_tr_b16 %0, %1 offset:1536" : "=v"(tv3) : "v"(va));
    asm volatile("ds_read_b64_tr_b16 %0, %1 offset:2048" : "=v"(tv4) : "v"(va));
    asm volatile("ds_read_b64_tr_b16 %0, %1 offset:2560" : "=v"(tv5) : "v"(va));
    asm volatile("ds_read_b64_tr_b16 %0, %1 offset:3072" : "=v"(tv6) : "v"(va));
    asm volatile("ds_read_b64_tr_b16 %0, %1 offset:3584" : "=v"(tv7) : "v"(va));
    asm volatile("s_waitcnt lgkmcnt(0)" ::: "memory");
    __builtin_amdgcn_sched_barrier(0);
    union { short8 s8; u32 u4[4]; } xb;
    xb.u4[0]=tv0.x; xb.u4[1]=tv0.y; xb.u4[2]=tv1.x; xb.u4[3]=tv1.y;
    c2[0] = __builtin_amdgcn_mfma_f32_16x16x32_bf16(pa, xb.s8, c2[0], 0,0,0);
    xb.u4[0]=tv2.x; xb.u4[1]=tv2.y; xb.u4[2]=tv3.x; xb.u4[3]=tv3.y;
    c2[1] = __builtin_amdgcn_mfma_f32_16x16x32_bf16(pa, xb.s8, c2[1], 0,0,0);
    xb.u4[0]=tv4.x; xb.u4[1]=tv4.y; xb.u4[2]=tv5.x; xb.u4[3]=tv5.y;
    c2[2] = __builtin_amdgcn_mfma_f32_16x16x32_bf16(pa, xb.s8, c2[2], 0,0,0);
    xb.u4[0]=tv6.x; xb.u4[1]=tv6.y; xb.u4[2]=tv7.x; xb.u4[3]=tv7.y;
    c2[3] = __builtin_amdgcn_mfma_f32_16x16x32_bf16(pa, xb.s8, c2[3], 0,0,0);
  }
}

// ---- the whole slot-attention loop: one block per batch, 8 waves, 3 iters ----
__global__ __launch_bounds__(512,1) void fused_sa(
    const float* __restrict__ inp, u16* __restrict__ xhat,
    const float* __restrict__ noise, const float* __restrict__ mu, const float* __restrict__ sigma,
    const float* __restrict__ Wqk,
    const float* __restrict__ lng, const float* __restrict__ lnb,
    const float* __restrict__ lnsg, const float* __restrict__ lnsb,
    const float* __restrict__ WihT, const float* __restrict__ WhhT,
    const float* __restrict__ bih, const float* __restrict__ bhh,
    const float* __restrict__ W1, const float* __restrict__ b1,
    const float* __restrict__ W2, const float* __restrict__ b2,
    const float* __restrict__ lnffg, const float* __restrict__ lnffb,
    const float* __restrict__ Wv,
    float* __restrict__ dout)
{
  __shared__ __align__(16) char smem[152320];
  int b = blockIdx.x, t = threadIdx.x;
  int w = t>>6, lane = t&63;
  int fr = lane&15, fq = lane>>4;
  int i = w, d = lane;                       // update-phase coords (slot, dim)

  char*  wbase = smem + w*9216;
  char*  abuf  = wbase + 8192;
  char*  qA    = smem + 73728;
  float* UL    = (float*)(smem + 75776);
  float* SL    = (float*)(smem + 92160);
  u16*   wih_l = (u16*)(smem + 92416);
  u16*   whh_l = (u16*)(smem + 116992);
  float* updL  = (float*)(smem + 141568);
  float* spL   = (float*)(smem + 143744);
  float* sfL   = (float*)(smem + 145920);
  float* hL    = (float*)(smem + 148096);

  // ---- init: stage GRU weights (bf16), zero qA pad, slots0 + q-tilde0 ----
  {
    const float4* wa = (const float4*)WihT;
    const float4* wb = (const float4*)WhhT;
    #pragma unroll
    for (int k2=0;k2<6;++k2){
      int idx = t + k2*512;                  // 0..3071 float4
      float4 va = wa[idx], vb = wb[idx];
      ((u32*)wih_l)[idx*2]   = (u32)f2bf(va.x) | ((u32)f2bf(va.y)<<16);
      ((u32*)wih_l)[idx*2+1] = (u32)f2bf(va.z) | ((u32)f2bf(va.w)<<16);
      ((u32*)whh_l)[idx*2]   = (u32)f2bf(vb.x) | ((u32)f2bf(vb.y)<<16);
      ((u32*)whh_l)[idx*2+1] = (u32)f2bf(vb.z) | ((u32)f2bf(vb.w)<<16);
    }
  }
  if (t < 256) ((u32*)(qA + 1024))[t] = 0;   // zero pad rows 8..15
  float sp = mu[d] + sigma[d]*noise[b*512 + t];
  {
    float m  = wsum64(sp)*(1.f/64.f);
    float df = sp - m;
    float vv = wsum64(df*df)*(1.f/64.f);
    float sv = df*rsqrtf(vv+EPS_LN)*lnsg[d] + lnsb[d];
    updL[i*68+d] = sv;
  }
  __syncthreads();
  {
    float qt = 0.f;
    #pragma unroll 8
    for (int dd=0; dd<64; ++dd) qt += updL[i*68+dd]*Wqk[dd*64 + d];
    *(u16*)(qA + ((i*128 + d*2) ^ ((i&7)<<4))) = f2bf(qt);
  }
  __syncthreads();

  long tbase = (long)b*128 + w*16;           // this wave's global 4KB-tile base

  for (int it=0; it<3; ++it){
    // ================= streaming phase (no block barriers) =================
    f32x4 c2[4];
    #pragma unroll
    for (int k2=0;k2<4;++k2) c2[k2] = (f32x4){0.f,0.f,0.f,0.f};
    float tsl[4] = {0.f,0.f,0.f,0.f};
    short8 qf0 = *(const short8*)(qA + ((fr*128 +  0 + fq*16) ^ ((fr&7)<<4)));
    short8 qf1 = *(const short8*)(qA + ((fr*128 + 64 + fq*16) ^ ((fr&7)<<4)));

    if (it == 0){
      // LN from f32 inputs (register double-buffered prefetch), build image,
      // direct scattered image store to global, attend.
      int r = lane>>1, hx = lane&1;
      const float4* xbase = (const float4*)(inp + ((long)b*N_ + w*512 + r)*64 + hx*32);
      float4 lg4[8], lb4[8];
      #pragma unroll
      for (int e=0;e<8;++e){
        lg4[e] = ((const float4*)(lng + hx*32))[e];
        lb4[e] = ((const float4*)(lnb + hx*32))[e];
      }
      int pbits = (((r>>2)&1)<<9) | (((r>>3)&3)<<7) | ((r&3)<<5);
      char* ibuf = wbase;

      auto proc = [&](const float4* xv4, int tile){
        float s=0.f, sq=0.f;
        #pragma unroll
        for (int c=0;c<8;++c){
          float4 f = xv4[c];
          s  += f.x+f.y+f.z+f.w;
          sq += f.x*f.x+f.y*f.y+f.z*f.z+f.w*f.w;
        }
        s  += __shfl_xor(s,1,64);
        sq += __shfl_xor(sq,1,64);
        float mean = s*(1.f/64.f);
        float inv  = rsqrtf(sq*(1.f/64.f) - mean*mean + EPS_LN);
        u32 pk[16];
        #pragma unroll
        for (int c=0;c<8;++c){
          float4 f = xv4[c]; float4 g = lg4[c]; float4 bb = lb4[c];
          pk[c*2]   = (u32)f2bf((f.x-mean)*inv*g.x + bb.x)
                    | ((u32)f2bf((f.y-mean)*inv*g.y + bb.y)<<16);
          pk[c*2+1] = (u32)f2bf((f.z-mean)*inv*g.z + bb.z)
                    | ((u32)f2bf((f.w-mean)*inv*g.w + bb.w)<<16);
        }
        char* gt = (char*)xhat + ((tbase+tile)<<12);
        #pragma unroll
        for (int hf=0; hf<2; ++hf){
          int dt = hx*2 + hf;
          uint4 v0; v0.x=pk[hf*8+0]; v0.y=pk[hf*8+1]; v0.z=pk[hf*8+2]; v0.w=pk[hf*8+3];
          uint4 v1; v1.x=pk[hf*8+4]; v1.y=pk[hf*8+5]; v1.z=pk[hf*8+6]; v1.w=pk[hf*8+7];
          int off = (dt<<10) | pbits;
          *(uint4*)(ibuf + off)      = v0;
          *(uint4*)(ibuf + off + 16) = v1;
          *(uint4*)(gt + off)        = v0;      // same bytes as the LDS image
          *(uint4*)(gt + off + 16)   = v1;
        }
        tile_attn(ibuf, abuf, qf0, qf1, fr, fq, c2, tsl);
      };

      float4 xe[8], xo[8];
      #pragma unroll
      for (int c=0;c<8;++c) xe[c] = xbase[c];            // tile 0
      for (int tt=0; tt<8; ++tt){
        const float4* nbo = xbase + (long)(2*tt+1)*512;  // prefetch odd tile
        #pragma unroll
        for (int c=0;c<8;++c) xo[c] = nbo[c];
        proc(xe, 2*tt);
        if (tt < 7){
          const float4* nbe = xbase + (long)(2*tt+2)*512; // prefetch next even
          #pragma unroll
          for (int c=0;c<8;++c) xe[c] = nbe[c];
        }
        proc(xo, 2*tt+1);
      }
      asm volatile("s_waitcnt vmcnt(0)" ::: "memory");  // image stores done
      __builtin_amdgcn_sched_barrier(0);
    } else {
      // gll16-streamed, per-wave double-buffered
      {
        const char* g0 = (const char*)xhat + (tbase<<12) + lane*16;
        #pragma unroll
        for (int j=0;j<4;++j) gll16(g0 + j*1024, wbase + j*1024);
      }
      #pragma unroll 2
      for (int tile=0; tile<16; ++tile){
        char* ibuf = wbase + (tile&1)*4096;
        if (tile < 15){
          const char* gn = (const char*)xhat + ((tbase+tile+1)<<12) + lane*16;
          char* ln = wbase + ((tile+1)&1)*4096;
          #pragma unroll
          for (int j=0;j<4;++j) gll16(gn + j*1024, ln + j*1024);
          asm volatile("s_waitcnt vmcnt(4)" ::: "memory");
        } else {
          asm volatile("s_waitcnt vmcnt(0)" ::: "memory");
        }
        __builtin_amdgcn_sched_barrier(0);
        tile_attn(ibuf, abuf, qf0, qf1, fr, fq, c2, tsl);
      }
    }
    // write per-wave partials
    if (fq < 2){
      #pragma unroll
      for (int dblk=0;dblk<4;++dblk){
        #pragma unroll
        for (int r2=0;r2<4;++r2)
          UL[w*512 + (fq*4+r2)*64 + dblk*16 + fr] = c2[dblk][r2];
      }
    }
    #pragma unroll
    for (int mk=1; mk<16; mk<<=1){
      tsl[0] += __shfl_xor(tsl[0], mk, 64);
      tsl[1] += __shfl_xor(tsl[1], mk, 64);
      tsl[2] += __shfl_xor(tsl[2], mk, 64);
      tsl[3] += __shfl_xor(tsl[3], mk, 64);
    }
    if (fr==0 && fq<2){
      SL[w*8 + fq*4+0] = tsl[0]; SL[w*8 + fq*4+1] = tsl[1];
      SL[w*8 + fq*4+2] = tsl[2]; SL[w*8 + fq*4+3] = tsl[3];
    }
    __syncthreads();

    // ================= update phase (all 512 threads) =================
    float u = 0.f, S = 0.f;
    #pragma unroll
    for (int cw=0; cw<8; ++cw){
      u += UL[cw*512 + i*64 + d];
      S += SL[cw*8 + i];
    }
    float ut = u / S;
    sfL[i*68+d] = ut;
    spL[i*68+d] = sp;
    __syncthreads();
    float upd = 0.f;
    #pragma unroll 8
    for (int dd=0; dd<64; ++dd) upd += sfL[i*68+dd]*Wv[dd*64 + d];
    updL[i*68+d] = upd;
    __syncthreads();
    float gx0 = bih[d], gx1 = bih[64+d], gx2 = bih[128+d];
    float gh0 = bhh[d], gh1 = bhh[64+d], gh2 = bhh[128+d];
    #pragma unroll 8
    for (int dd=0; dd<64; ++dd){
      float uv = updL[i*68+dd];
      float sv = spL[i*68+dd];
      gx0 += uv*bf_lo((u32)wih_l[dd*192 + d]);
      gx1 += uv*bf_lo((u32)wih_l[dd*192 + 64 + d]);
      gx2 += uv*bf_lo((u32)wih_l[dd*192 + 128 + d]);
      gh0 += sv*bf_lo((u32)whh_l[dd*192 + d]);
      gh1 += sv*bf_lo((u32)whh_l[dd*192 + 64 + d]);
      gh2 += sv*bf_lo((u32)whh_l[dd*192 + 128 + d]);
    }
    float rg = 1.f/(1.f+__expf(-(gx0+gh0)));
    float zg = 1.f/(1.f+__expf(-(gx1+gh1)));
    float ng = tanhf(gx2 + rg*gh2);
    float sn = (1.f-zg)*ng + zg*sp;
    float m1 = wsum64(sn)*(1.f/64.f);
    float df = sn-m1;
    float vv = wsum64(df*df)*(1.f/64.f);
    float sf = df*rsqrtf(vv+EPS_LN)*lnffg[d] + lnffb[d];
    sfL[i*68+d] = sf;
    __syncthreads();
    float h0 = b1[d], h1 = b1[64+d];
    #pragma unroll 8
    for (int dd=0;dd<64;++dd){
      float sv = sfL[i*68+dd];
      h0 += sv*W1[dd*128 + d];
      h1 += sv*W1[dd*128 + 64 + d];
    }
    h0 = fmaxf(h0, 0.f); h1 = fmaxf(h1, 0.f);
    hL[i*132+d] = h0; hL[i*132+64+d] = h1;
    __syncthreads();
    float o = b2[d];
    #pragma unroll 8
    for (int hh=0; hh<128; ++hh) o += hL[i*132+hh]*W2[hh*64 + d];
    float out = sf + o;
    sp = out;
    if (it == 2){
      dout[b*512 + t] = out;
    } else {
      float m2 = wsum64(out)*(1.f/64.f);
      float d2 = out-m2;
      float v2 = wsum64(d2*d2)*(1.f/64.f);
      float sq = d2*rsqrtf(v2+EPS_LN)*lnsg[d] + lnsb[d];
      updL[i*68+d] = sq;
      __syncthreads();
      float qt = 0.f;
      #pragma unroll 8
      for (int dd=0;dd<64;++dd) qt += updL[i*68+dd]*Wqk[dd*64 + d];
      *(u16*)(qA + ((i*128 + d*2) ^ ((i&7)<<4))) = f2bf(qt);
      __syncthreads();
    }
  }
}

extern "C" void kernel_launch(void* const* d_in, const int* in_sizes, int n_in,
                              void* d_out, int out_size, void* d_ws, size_t ws_size,
                              hipStream_t stream){
  const float* inp   = (const float*)d_in[0];
  const float* noise = (const float*)d_in[1];
  const float* mu    = (const float*)d_in[2];
  const float* sigma = (const float*)d_in[3];
  const float* Wq    = (const float*)d_in[4];
  const float* Wk    = (const float*)d_in[5];
  const float* Wv    = (const float*)d_in[6];
  const float* Wih   = (const float*)d_in[7];
  const float* Whh   = (const float*)d_in[8];
  const float* bih   = (const float*)d_in[9];
  const float* bhh   = (const float*)d_in[10];
  const float* W1    = (const float*)d_in[11];
  const float* b1    = (const float*)d_in[12];
  const float* W2    = (const float*)d_in[13];
  const float* b2    = (const float*)d_in[14];
  const float* lnig  = (const float*)d_in[15];
  const float* lnib  = (const float*)d_in[16];
  const float* lnsg  = (const float*)d_in[17];
  const float* lnsb  = (const float*)d_in[18];
  const float* lnffg = (const float*)d_in[19];
  const float* lnffb = (const float*)d_in[20];
  float* out = (float*)d_out;

  char* ws = (char*)d_ws;
  u16*   xhat = (u16*)(ws);                        // 67108864 B (4KB tile images)
  float* WihT = (float*)(ws + 67108864);           // 49152 B
  float* WhhT = (float*)(ws + 67158016);           // 49152 B
  float* Wqk  = (float*)(ws + 67207168);           // 16384 B -> ~67.2 MB total

  prep_t<<<64,256,0,stream>>>(Wih, Whh, Wq, Wk, WihT, WhhT, Wqk);
  fused_sa<<<B_,512,0,stream>>>(inp, xhat, noise, mu, sigma, Wqk,
                                lnig, lnib, lnsg, lnsb,
                                WihT, WhhT, bih, bhh,
                                W1, b1, W2, b2, lnffg, lnffb, Wv, out);
}

// Round 18
// 130.153 us; speedup vs baseline: 2.4005x; 1.1365x over previous
//
#include <hip/hip_runtime.h>
#include <hip/hip_bf16.h>

typedef unsigned int u32;
typedef unsigned short u16;
typedef __attribute__((ext_vector_type(8))) short short8;
typedef __attribute__((ext_vector_type(4))) float f32x4;
typedef __attribute__((ext_vector_type(2))) u32 u32x2;

#define B_      128
#define N_      4096
#define K_      8
#define SCALE_  0.125f
#define EPS_A   1e-8f
#define EPS_LN  1e-5f

__device__ __forceinline__ float bf_lo(u32 u){ union{u32 v; float f;} x; x.v = u<<16; return x.f; }
__device__ __forceinline__ u16 f2bf(float f){
  union{float f; u32 v;} x; x.f = f;
  u32 v = x.v;
  return (u16)((v + 0x7fffu + ((v>>16)&1u))>>16);   // RNE
}
__device__ __forceinline__ float wsum64(float v){
  #pragma unroll
  for (int off=32; off; off>>=1) v += __shfl_xor(v, off, 64);
  return v;
}
__device__ __forceinline__ void gll16(const void* g, void* l){
  __builtin_amdgcn_global_load_lds(
      (const __attribute__((address_space(1))) void*)g,
      (__attribute__((address_space(3))) void*)l, 16, 0, 0);
}

// ---- one-time prep: transpose GRU weights; Wqk = Wq @ Wk^T ; zero sync flags ----
__global__ void prep_t(const float* __restrict__ Wih, const float* __restrict__ Whh,
                       const float* __restrict__ Wq,  const float* __restrict__ Wk,
                       float* __restrict__ WihT, float* __restrict__ WhhT,
                       float* __restrict__ Wqk, int* __restrict__ flags){
  int t = threadIdx.x;
  if (blockIdx.x == 0 && t < B_) flags[t] = 0;
  if (blockIdx.x < 48){
    int idx = blockIdx.x*256 + t;            // 12288 = 192*64
    int g = idx>>6, d = idx&63;
    WihT[d*192+g] = Wih[idx];
    WhhT[d*192+g] = Whh[idx];
  } else {
    __shared__ float WkL[64*65];
    int bi = blockIdx.x - 48;                // 0..15
    #pragma unroll
    for (int k=0;k<16;++k){
      int idx = t + k*256;
      int d = idx>>6, m = idx&63;
      WkL[m*65+d] = Wk[idx];
    }
    __syncthreads();
    int a = bi*4 + (t>>6), d = t&63;
    float acc = 0.f;
    #pragma unroll 8
    for (int m=0;m<64;++m) acc += Wq[a*64+m]*WkL[m*65+d];
    Wqk[a*64+d] = acc;
  }
}

// per-tile attention phases (R11-verified byte math; 32-pos x 64-d image in ibuf)
__device__ __forceinline__ void tile_attn(
    char* ibuf, char* abuf, short8 qf0, short8 qf1,
    int fr, int fq, f32x4* c2, float* tsl)
{
  // ph1: dots[16 slots][32 pos]
  f32x4 c1[2];
  #pragma unroll
  for (int nt=0;nt<2;++nt){
    c1[nt] = (f32x4){0.f,0.f,0.f,0.f};
    #pragma unroll
    for (int kk=0;kk<2;++kk){
      int byte = ((kk*2+(fq>>1))<<10) | (((fr>>2)&1)<<9)
               | ((nt*2+(fr>>3))<<7) | ((fr&3)<<5) | ((fq&1)<<4);
      short8 xf = *(const short8*)(ibuf + byte);
      c1[nt] = __builtin_amdgcn_mfma_f32_16x16x32_bf16(kk?qf1:qf0, xf, c1[nt], 0,0,0);
    }
  }
  // softmax over slots; attn -> abuf [16 slots][32 pos] bf16
  #pragma unroll
  for (int nt=0;nt<2;++nt){
    float d0 = c1[nt][0]*SCALE_, d1 = c1[nt][1]*SCALE_;
    float d2 = c1[nt][2]*SCALE_, d3 = c1[nt][3]*SCALE_;
    float m = fmaxf(fmaxf(d0,d1), fmaxf(d2,d3));
    m = fmaxf(m, __shfl_xor(m, 16, 64));
    float e0 = __expf(d0-m), e1 = __expf(d1-m), e2 = __expf(d2-m), e3 = __expf(d3-m);
    float sl = e0+e1+e2+e3;
    float inv = 1.f/(sl + __shfl_xor(sl, 16, 64));
    float a0 = e0*inv + EPS_A, a1 = e1*inv + EPS_A;
    float a2 = e2*inv + EPS_A, a3 = e3*inv + EPS_A;
    tsl[0]+=a0; tsl[1]+=a1; tsl[2]+=a2; tsl[3]+=a3;
    int pos2 = (nt*16 + fr)*2;
    *(u16*)(abuf + (((fq*4+0)*64 + pos2) ^ (0<<4))) = f2bf(a0);
    *(u16*)(abuf + (((fq*4+1)*64 + pos2) ^ (1<<4))) = f2bf(a1);
    *(u16*)(abuf + (((fq*4+2)*64 + pos2) ^ (2<<4))) = f2bf(a2);
    *(u16*)(abuf + (((fq*4+3)*64 + pos2) ^ (3<<4))) = f2bf(a3);
  }
  asm volatile("s_waitcnt lgkmcnt(0)" ::: "memory");
  __builtin_amdgcn_sched_barrier(0);
  // ph2: U[slot][d] += attn @ x^T  (all 64 d, K=32 pos)
  {
    short8 pa = *(const short8*)(abuf + ((fr*64 + fq*16) ^ ((fr&3)<<4)));
    u32 va = (u32)(size_t)ibuf + (fq<<7) + (fr<<1);
    u32x2 tv0,tv1,tv2,tv3,tv4,tv5,tv6,tv7;
    asm volatile("ds_read_b64_tr_b16 %0, %1 offset:0"    : "=v"(tv0) : "v"(va));
    asm volatile("ds_read_b64_tr_b16 %0, %1 offset:512"  : "=v"(tv1) : "v"(va));
    asm volatile("ds_read_b64_tr_b16 %0, %1 offset:1024" : "=v"(tv2) : "v"(va));
    asm volatile("ds_read_b64_tr_b16 %0, %1 offset:1536" : "=v"(tv3) : "v"(va));
    asm volatile("ds_read_b64_tr_b16 %0, %1 offset:2048" : "=v"(tv4) : "v"(va));
    asm volatile("ds_read_b64_tr_b16 %0, %1 offset:2560" : "=v"(tv5) : "v"(va));
    asm volatile("ds_read_b64_tr_b16 %0, %1 offset:3072" : "=v"(tv6) : "v"(va));
    asm volatile("ds_read_b64_tr_b16 %0, %1 offset:3584" : "=v"(tv7) : "v"(va));
    asm volatile("s_waitcnt lgkmcnt(0)" ::: "memory");
    __builtin_amdgcn_sched_barrier(0);
    union { short8 s8; u32 u4[4]; } xb;
    xb.u4[0]=tv0.x; xb.u4[1]=tv0.y; xb.u4[2]=tv1.x; xb.u4[3]=tv1.y;
    c2[0] = __builtin_amdgcn_mfma_f32_16x16x32_bf16(pa, xb.s8, c2[0], 0,0,0);
    xb.u4[0]=tv2.x; xb.u4[1]=tv2.y; xb.u4[2]=tv3.x; xb.u4[3]=tv3.y;
    c2[1] = __builtin_amdgcn_mfma_f32_16x16x32_bf16(pa, xb.s8, c2[1], 0,0,0);
    xb.u4[0]=tv4.x; xb.u4[1]=tv4.y; xb.u4[2]=tv5.x; xb.u4[3]=tv5.y;
    c2[2] = __builtin_amdgcn_mfma_f32_16x16x32_bf16(pa, xb.s8, c2[2], 0,0,0);
    xb.u4[0]=tv6.x; xb.u4[1]=tv6.y; xb.u4[2]=tv7.x; xb.u4[3]=tv7.y;
    c2[3] = __builtin_amdgcn_mfma_f32_16x16x32_bf16(pa, xb.s8, c2[3], 0,0,0);
  }
}

// ---- whole slot-attention loop: pair (bid, bid^128) on the SAME XCD ----
__global__ __launch_bounds__(512,1) void fused_sa(
    const float* __restrict__ inp, u16* __restrict__ xhat,
    const float* __restrict__ noise, const float* __restrict__ mu, const float* __restrict__ sigma,
    const float* __restrict__ Wqk,
    const float* __restrict__ lng, const float* __restrict__ lnb,
    const float* __restrict__ lnsg, const float* __restrict__ lnsb,
    const float* __restrict__ WihT, const float* __restrict__ WhhT,
    const float* __restrict__ bih, const float* __restrict__ bhh,
    const float* __restrict__ W1, const float* __restrict__ b1,
    const float* __restrict__ W2, const float* __restrict__ b2,
    const float* __restrict__ lnffg, const float* __restrict__ lnffb,
    const float* __restrict__ Wv,
    float* __restrict__ PUg, float* __restrict__ PSg, int* __restrict__ flags,
    float* __restrict__ dout)
{
  __shared__ __align__(16) char smem[152320];
  int bid = blockIdx.x, t = threadIdx.x;
  int b = bid & 127, half = bid >> 7;        // pair (bid, bid^128): same XCD (bid%8 equal)
  int w = t>>6, lane = t&63;
  int fr = lane&15, fq = lane>>4;
  int i = w, d = lane;                       // update-phase coords (slot, dim)

  char*  wbase = smem + w*9216;
  char*  abuf  = wbase + 8192;
  char*  qA    = smem + 73728;
  float* UL    = (float*)(smem + 75776);
  float* SL    = (float*)(smem + 92160);
  u16*   wih_l = (u16*)(smem + 92416);
  u16*   whh_l = (u16*)(smem + 116992);
  float* updL  = (float*)(smem + 141568);
  float* spL   = (float*)(smem + 143744);
  float* sfL   = (float*)(smem + 145920);
  float* hL    = (float*)(smem + 148096);

  // ---- init: stage GRU weights (bf16), zero qA pad, slots0 + q-tilde0 ----
  {
    const float4* wa = (const float4*)WihT;
    const float4* wb = (const float4*)WhhT;
    #pragma unroll
    for (int k2=0;k2<6;++k2){
      int idx = t + k2*512;                  // 0..3071 float4
      float4 va = wa[idx], vb = wb[idx];
      ((u32*)wih_l)[idx*2]   = (u32)f2bf(va.x) | ((u32)f2bf(va.y)<<16);
      ((u32*)wih_l)[idx*2+1] = (u32)f2bf(va.z) | ((u32)f2bf(va.w)<<16);
      ((u32*)whh_l)[idx*2]   = (u32)f2bf(vb.x) | ((u32)f2bf(vb.y)<<16);
      ((u32*)whh_l)[idx*2+1] = (u32)f2bf(vb.z) | ((u32)f2bf(vb.w)<<16);
    }
  }
  if (t < 256) ((u32*)(qA + 1024))[t] = 0;   // zero pad rows 8..15
  float sp = mu[d] + sigma[d]*noise[b*512 + t];
  {
    float m  = wsum64(sp)*(1.f/64.f);
    float df = sp - m;
    float vv = wsum64(df*df)*(1.f/64.f);
    float sv = df*rsqrtf(vv+EPS_LN)*lnsg[d] + lnsb[d];
    updL[i*68+d] = sv;
  }
  __syncthreads();
  {
    float qt = 0.f;
    #pragma unroll 8
    for (int dd=0; dd<64; ++dd) qt += updL[i*68+dd]*Wqk[dd*64 + d];
    *(u16*)(qA + ((i*128 + d*2) ^ ((i&7)<<4))) = f2bf(qt);
  }
  __syncthreads();

  long tbase = (long)b*128 + half*64 + w*8;  // this wave's global 4KB-tile base

  for (int it=0; it<3; ++it){
    // ================= streaming phase (no block barriers) =================
    f32x4 c2[4];
    #pragma unroll
    for (int k2=0;k2<4;++k2) c2[k2] = (f32x4){0.f,0.f,0.f,0.f};
    float tsl[4] = {0.f,0.f,0.f,0.f};
    short8 qf0 = *(const short8*)(qA + ((fr*128 +  0 + fq*16) ^ ((fr&7)<<4)));
    short8 qf1 = *(const short8*)(qA + ((fr*128 + 64 + fq*16) ^ ((fr&7)<<4)));

    if (it == 0){
      // LN from f32 inputs, build image, linear image store to global, attend
      for (int tile=0; tile<8; ++tile){
        char* ibuf = wbase;
        {
          int r = lane>>1, hx = lane&1;
          const float4* xr = (const float4*)(inp +
              ((long)b*N_ + half*2048 + w*256 + tile*32 + r)*64 + hx*32);
          float xv[32]; float s=0.f, sq=0.f;
          #pragma unroll
          for (int c=0;c<8;++c){
            float4 f = xr[c];
            xv[c*4+0]=f.x; xv[c*4+1]=f.y; xv[c*4+2]=f.z; xv[c*4+3]=f.w;
            s  += f.x+f.y+f.z+f.w;
            sq += f.x*f.x+f.y*f.y+f.z*f.z+f.w*f.w;
          }
          s  += __shfl_xor(s,1,64);
          sq += __shfl_xor(sq,1,64);
          float mean = s*(1.f/64.f);
          float inv  = rsqrtf(sq*(1.f/64.f) - mean*mean + EPS_LN);
          float lgv[32], lbv[32];
          {
            const float4* g4 = (const float4*)(lng + hx*32);
            const float4* b4 = (const float4*)(lnb + hx*32);
            #pragma unroll
            for (int e=0;e<8;++e){
              float4 gv = g4[e], bv = b4[e];
              lgv[e*4+0]=gv.x; lgv[e*4+1]=gv.y; lgv[e*4+2]=gv.z; lgv[e*4+3]=gv.w;
              lbv[e*4+0]=bv.x; lbv[e*4+1]=bv.y; lbv[e*4+2]=bv.z; lbv[e*4+3]=bv.w;
            }
          }
          u32 pk[16];
          #pragma unroll
          for (int e=0;e<16;++e){
            float a0 = (xv[e*2]  -mean)*inv*lgv[e*2]   + lbv[e*2];
            float a1 = (xv[e*2+1]-mean)*inv*lgv[e*2+1] + lbv[e*2+1];
            pk[e] = (u32)f2bf(a0) | ((u32)f2bf(a1)<<16);
          }
          int pbits = (((r>>2)&1)<<9) | (((r>>3)&3)<<7) | ((r&3)<<5);
          #pragma unroll
          for (int hf=0; hf<2; ++hf){
            int dt = hx*2 + hf;
            uint4 v0; v0.x=pk[hf*8+0]; v0.y=pk[hf*8+1]; v0.z=pk[hf*8+2]; v0.w=pk[hf*8+3];
            uint4 v1; v1.x=pk[hf*8+4]; v1.y=pk[hf*8+5]; v1.z=pk[hf*8+6]; v1.w=pk[hf*8+7];
            *(uint4*)(ibuf + ((dt<<10) | pbits))      = v0;
            *(uint4*)(ibuf + ((dt<<10) | pbits) + 16) = v1;
          }
          asm volatile("s_waitcnt lgkmcnt(0)" ::: "memory");
          __builtin_amdgcn_sched_barrier(0);
          char* gim = (char*)xhat + ((tbase+tile)<<12) + lane*16;
          #pragma unroll
          for (int j=0;j<4;++j)
            *(uint4*)(gim + j*1024) = *(const uint4*)(ibuf + lane*16 + j*1024);
        }
        tile_attn(ibuf, abuf, qf0, qf1, fr, fq, c2, tsl);
      }
      asm volatile("s_waitcnt vmcnt(0)" ::: "memory");  // image stores done
      __builtin_amdgcn_sched_barrier(0);
    } else {
      // gll16-streamed, per-wave double-buffered
      {
        const char* g0 = (const char*)xhat + (tbase<<12) + lane*16;
        #pragma unroll
        for (int j=0;j<4;++j) gll16(g0 + j*1024, wbase + j*1024);
      }
      #pragma unroll 2
      for (int tile=0; tile<8; ++tile){
        char* ibuf = wbase + (tile&1)*4096;
        if (tile < 7){
          const char* gn = (const char*)xhat + ((tbase+tile+1)<<12) + lane*16;
          char* ln = wbase + ((tile+1)&1)*4096;
          #pragma unroll
          for (int j=0;j<4;++j) gll16(gn + j*1024, ln + j*1024);
          asm volatile("s_waitcnt vmcnt(4)" ::: "memory");
        } else {
          asm volatile("s_waitcnt vmcnt(0)" ::: "memory");
        }
        __builtin_amdgcn_sched_barrier(0);
        tile_attn(ibuf, abuf, qf0, qf1, fr, fq, c2, tsl);
      }
    }
    // write per-wave partials to LDS
    if (fq < 2){
      #pragma unroll
      for (int dblk=0;dblk<4;++dblk){
        #pragma unroll
        for (int r2=0;r2<4;++r2)
          UL[w*512 + (fq*4+r2)*64 + dblk*16 + fr] = c2[dblk][r2];
      }
    }
    #pragma unroll
    for (int mk=1; mk<16; mk<<=1){
      tsl[0] += __shfl_xor(tsl[0], mk, 64);
      tsl[1] += __shfl_xor(tsl[1], mk, 64);
      tsl[2] += __shfl_xor(tsl[2], mk, 64);
      tsl[3] += __shfl_xor(tsl[3], mk, 64);
    }
    if (fr==0 && fq<2){
      SL[w*8 + fq*4+0] = tsl[0]; SL[w*8 + fq*4+1] = tsl[1];
      SL[w*8 + fq*4+2] = tsl[2]; SL[w*8 + fq*4+3] = tsl[3];
    }
    __syncthreads();

    // ===== same-XCD exchange: relaxed stores -> vmcnt -> flag -> relaxed loads =====
    float u = 0.f, S = 0.f;
    #pragma unroll
    for (int cw=0; cw<8; ++cw){
      u += UL[cw*512 + i*64 + d];
      S += SL[cw*8 + i];
    }
    {
      long pbase = ((long)it*256 + bid);
      __hip_atomic_store(&PUg[pbase*512 + t], u, __ATOMIC_RELAXED, __HIP_MEMORY_SCOPE_AGENT);
      if (d == 0)
        __hip_atomic_store(&PSg[pbase*8 + i], S, __ATOMIC_RELAXED, __HIP_MEMORY_SCOPE_AGENT);
    }
    asm volatile("s_waitcnt vmcnt(0)" ::: "memory");   // partials retired to L2
    __syncthreads();
    if (t == 0){
      __hip_atomic_fetch_add(&flags[b], 1, __ATOMIC_RELAXED, __HIP_MEMORY_SCOPE_AGENT);
      while (__hip_atomic_load(&flags[b], __ATOMIC_RELAXED, __HIP_MEMORY_SCOPE_AGENT) < 2*(it+1))
        __builtin_amdgcn_s_sleep(2);
    }
    __syncthreads();
    {
      long obase = ((long)it*256 + (bid ^ 128));
      u += __hip_atomic_load(&PUg[obase*512 + t], __ATOMIC_RELAXED, __HIP_MEMORY_SCOPE_AGENT);
      S += __hip_atomic_load(&PSg[obase*8 + i], __ATOMIC_RELAXED, __HIP_MEMORY_SCOPE_AGENT);
    }

    // ================= update phase (redundant in both halves) =================
    float ut = u / S;
    sfL[i*68+d] = ut;
    spL[i*68+d] = sp;
    __syncthreads();
    float upd = 0.f;
    #pragma unroll 8
    for (int dd=0; dd<64; ++dd) upd += sfL[i*68+dd]*Wv[dd*64 + d];
    updL[i*68+d] = upd;
    __syncthreads();
    float gx0 = bih[d], gx1 = bih[64+d], gx2 = bih[128+d];
    float gh0 = bhh[d], gh1 = bhh[64+d], gh2 = bhh[128+d];
    #pragma unroll 8
    for (int dd=0; dd<64; ++dd){
      float uv = updL[i*68+dd];
      float sv = spL[i*68+dd];
      gx0 += uv*bf_lo((u32)wih_l[dd*192 + d]);
      gx1 += uv*bf_lo((u32)wih_l[dd*192 + 64 + d]);
      gx2 += uv*bf_lo((u32)wih_l[dd*192 + 128 + d]);
      gh0 += sv*bf_lo((u32)whh_l[dd*192 + d]);
      gh1 += sv*bf_lo((u32)whh_l[dd*192 + 64 + d]);
      gh2 += sv*bf_lo((u32)whh_l[dd*192 + 128 + d]);
    }
    float rg = 1.f/(1.f+__expf(-(gx0+gh0)));
    float zg = 1.f/(1.f+__expf(-(gx1+gh1)));
    float ng = tanhf(gx2 + rg*gh2);
    float sn = (1.f-zg)*ng + zg*sp;
    float m1 = wsum64(sn)*(1.f/64.f);
    float df = sn-m1;
    float vv = wsum64(df*df)*(1.f/64.f);
    float sf = df*rsqrtf(vv+EPS_LN)*lnffg[d] + lnffb[d];
    sfL[i*68+d] = sf;
    __syncthreads();
    float h0 = b1[d], h1 = b1[64+d];
    #pragma unroll 8
    for (int dd=0;dd<64;++dd){
      float sv = sfL[i*68+dd];
      h0 += sv*W1[dd*128 + d];
      h1 += sv*W1[dd*128 + 64 + d];
    }
    h0 = fmaxf(h0, 0.f); h1 = fmaxf(h1, 0.f);
    hL[i*132+d] = h0; hL[i*132+64+d] = h1;
    __syncthreads();
    float o = b2[d];
    #pragma unroll 8
    for (int hh=0; hh<128; ++hh) o += hL[i*132+hh]*W2[hh*64 + d];
    float out = sf + o;
    sp = out;
    if (it == 2){
      if (half == 0) dout[b*512 + t] = out;
    } else {
      float m2 = wsum64(out)*(1.f/64.f);
      float d2 = out-m2;
      float v2 = wsum64(d2*d2)*(1.f/64.f);
      float sq = d2*rsqrtf(v2+EPS_LN)*lnsg[d] + lnsb[d];
      updL[i*68+d] = sq;
      __syncthreads();
      float qt = 0.f;
      #pragma unroll 8
      for (int dd=0;dd<64;++dd) qt += updL[i*68+dd]*Wqk[dd*64 + d];
      *(u16*)(qA + ((i*128 + d*2) ^ ((i&7)<<4))) = f2bf(qt);
      __syncthreads();
    }
  }
}

extern "C" void kernel_launch(void* const* d_in, const int* in_sizes, int n_in,
                              void* d_out, int out_size, void* d_ws, size_t ws_size,
                              hipStream_t stream){
  const float* inp   = (const float*)d_in[0];
  const float* noise = (const float*)d_in[1];
  const float* mu    = (const float*)d_in[2];
  const float* sigma = (const float*)d_in[3];
  const float* Wq    = (const float*)d_in[4];
  const float* Wk    = (const float*)d_in[5];
  const float* Wv    = (const float*)d_in[6];
  const float* Wih   = (const float*)d_in[7];
  const float* Whh   = (const float*)d_in[8];
  const float* bih   = (const float*)d_in[9];
  const float* bhh   = (const float*)d_in[10];
  const float* W1    = (const float*)d_in[11];
  const float* b1    = (const float*)d_in[12];
  const float* W2    = (const float*)d_in[13];
  const float* b2    = (const float*)d_in[14];
  const float* lnig  = (const float*)d_in[15];
  const float* lnib  = (const float*)d_in[16];
  const float* lnsg  = (const float*)d_in[17];
  const float* lnsb  = (const float*)d_in[18];
  const float* lnffg = (const float*)d_in[19];
  const float* lnffb = (const float*)d_in[20];
  float* out = (float*)d_out;

  char* ws = (char*)d_ws;
  u16*   xhat  = (u16*)(ws);                       // 67108864 B (4KB tile images)
  float* WihT  = (float*)(ws + 67108864);          // 49152 B
  float* WhhT  = (float*)(ws + 67158016);          // 49152 B
  float* Wqk   = (float*)(ws + 67207168);          // 16384 B
  float* PUg   = (float*)(ws + 67223552);          // 3*256*512*4 = 1572864 B
  float* PSg   = (float*)(ws + 68796416);          // 3*256*8*4   = 24576 B
  int*   flags = (int*)(ws + 68820992);            // 512 B -> ~68.8 MB total

  prep_t<<<64,256,0,stream>>>(Wih, Whh, Wq, Wk, WihT, WhhT, Wqk, flags);
  fused_sa<<<2*B_,512,0,stream>>>(inp, xhat, noise, mu, sigma, Wqk,
                                  lnig, lnib, lnsg, lnsb,
                                  WihT, WhhT, bih, bhh,
                                  W1, b1, W2, b2, lnffg, lnffb, Wv,
                                  PUg, PSg, flags, out);
}